// Round 8
// baseline (147.165 us; speedup 1.0000x reference)
//
#include <hip/hip_runtime.h>
#include <hip/hip_bf16.h>

#define TOKENS 8192
#define D_IN   256
#define HDIM   1024
#define ODIM   768
#define KPACK  1088   // 4*256 data cols + bias chunk (chunk 128..135) -> 17 x BK=64
#define NCHUNK 136    // KPACK/8
#define NCLS   11     // valid expert-mask classes
#define MCAP   11008  // 43 tiles * 256 rows (max padded M)
#define MTILES 43
#define G1BLK  301    // 43 * 7

typedef short bf16x8 __attribute__((ext_vector_type(8)));
typedef float f32x4  __attribute__((ext_vector_type(4)));

static __device__ __forceinline__ ushort f2b(float f) {
    union { __hip_bfloat16 b; ushort u; } cv;
    cv.b = __float2bfloat16(f);
    return cv.u;
}
static __device__ __forceinline__ float b2f(ushort u) {
    union { ushort u; __hip_bfloat16 b; } cv;
    cv.u = u;
    return __bfloat162float(cv.b);
}

// direct global->LDS DMA, 16B/lane; LDS dest = wave-uniform base + lane*16
static __device__ __forceinline__ void stage16(const ushort* g, ushort* l) {
    __builtin_amdgcn_global_load_lds(
        (const __attribute__((address_space(1))) void*)g,
        (__attribute__((address_space(3))) void*)l, 16, 0, 0);
}

// tanh-form GELU (max dev from exact erf-GELU ~3e-4)
static __device__ __forceinline__ float gelu_f(float v) {
    float y = 0.7978845608f * v * (1.f + 0.044715f * v * v);
    return v - v / (__expf(2.f * y) + 1.f);
}

// ---- K0a: routing: wmap, class mask, per-block class histogram -------------
__global__ __launch_bounds__(256) void k_route(
    const float* __restrict__ ew, const int* __restrict__ ei,
    float* __restrict__ wmap, int* __restrict__ classid, int* __restrict__ bhist) {
    __shared__ int h[16];
    int t = threadIdx.x;
    if (t < 16) h[t] = 0;
    __syncthreads();
    int n = blockIdx.x * 256 + t;
    int   i0 = ei[2 * n], i1 = ei[2 * n + 1];
    float w0 = ew[2 * n], w1 = ew[2 * n + 1];
    bool v0 = (unsigned)i0 < 4u, v1 = (unsigned)i1 < 4u;
    float rs = (v0 ? w0 : 0.f) + (v1 ? w1 : 0.f);
    if (rs == 0.f) rs = 1.f;
    float o0 = v0 ? w0 / rs : 0.f;
    float o1 = v1 ? w1 / rs : 0.f;
#pragma unroll
    for (int e = 0; e < 4; ++e) {
        float m = 0.f;
        if (v0 && i0 == e) m += o0;
        if (v1 && i1 == e) m += o1;
        wmap[e * TOKENS + n] = m;
    }
    int msk = (v0 ? (1 << i0) : 0) | (v1 ? (1 << i1) : 0);
    classid[n] = msk;
    atomicAdd(&h[msk], 1);
    __syncthreads();
    if (t < 16) bhist[blockIdx.x * 16 + t] = h[t];
}

// ---- K0b: init tokof to -1 --------------------------------------------------
__global__ __launch_bounds__(256) void k_init(int* __restrict__ tokof) {
    int i = blockIdx.x * 256 + threadIdx.x;
    if (i < MCAP) tokof[i] = -1;
}

// ---- K0c: scan: class totals -> 256-aligned bases (descending weight order)
__global__ __launch_bounds__(64) void k_scan(
    const int* __restrict__ bhist, int* __restrict__ pbase,
    int* __restrict__ cnt, int* __restrict__ cursor) {
    const int cm[NCLS] = {12, 10, 9, 6, 5, 3, 8, 4, 2, 1, 0};  // heavy->light
    int t = threadIdx.x;
    __shared__ int tot[NCLS];
    if (t < NCLS) {
        int m = cm[t], s = 0;
        for (int b = 0; b < 32; ++b) s += bhist[b * 16 + m];
        tot[t] = s;
    }
    __syncthreads();
    if (t == 0) {
        int acc = 0;
        for (int k = 0; k < NCLS; ++k) {
            pbase[k] = acc; cursor[k] = acc; cnt[k] = tot[k];
            acc += (tot[k] + 255) & ~255;
        }
        pbase[NCLS] = acc;
    }
}

// ---- K0d: scatter tokens into class-sorted slots ---------------------------
__global__ __launch_bounds__(256) void k_scatter(
    const int* __restrict__ classid, int* __restrict__ cursor,
    int* __restrict__ sortpos, int* __restrict__ tokof) {
    const int m2k[16] = {10, 9, 8, 5, 7, 4, 3, 0, 6, 2, 1, 0, 0, 0, 0, 0};
    int n = blockIdx.x * 256 + threadIdx.x;
    int k = m2k[classid[n]];
    int p = atomicAdd(&cursor[k], 1);
    sortpos[n] = p;
    tokof[p] = n;
}

// ---- K0e: pack A'' into sorted rows (bf16) ---------------------------------
__global__ __launch_bounds__(256) void k_pack_a(
    const float* __restrict__ xf, const float* __restrict__ wmap,
    const int* __restrict__ sortpos, ushort* __restrict__ Ap) {
    int gid = blockIdx.x * 256 + threadIdx.x;   // 8192*136 items
    int n  = gid / NCHUNK;
    int c8 = gid - n * NCHUNK;
    ushort o[8] __attribute__((aligned(16))) = {0, 0, 0, 0, 0, 0, 0, 0};
    if (c8 < 128) {
        int e  = c8 >> 5;
        int d0 = (c8 & 31) << 3;
        float w = wmap[e * TOKENS + n];
        bool keep = (d0 & 127) < 32 * (e + 1);
        if (w != 0.f && keep) {
            const float* s = xf + ((size_t)e * TOKENS + n) * D_IN + d0;
#pragma unroll
            for (int j = 0; j < 8; ++j) {
                float v = s[j];
                if (!(v == v)) v = 0.f;   // nan_to_num
                o[j] = f2b(w * v);
            }
        }
    } else if (c8 == 128) {
#pragma unroll
        for (int j = 0; j < 4; ++j) o[j] = f2b(wmap[j * TOKENS + n]);
    }
    int row = sortpos[n];
    *(uint4*)(Ap + (size_t)row * KPACK + c8 * 8) = *(const uint4*)o;
}

// ---- K0f: pack B'' = [W_hid;W_res], bias in K-cols 1024..1027 --------------
__global__ __launch_bounds__(256) void k_pack_b(
    const float* __restrict__ Whid, const float* __restrict__ bhid,
    const float* __restrict__ Wres, const float* __restrict__ bres,
    ushort* __restrict__ Bp) {
    int gid = blockIdx.x * 256 + threadIdx.x;   // 1792*136 items
    int o_ = gid / NCHUNK;
    int c8 = gid - o_ * NCHUNK;
    ushort v[8] __attribute__((aligned(16))) = {0, 0, 0, 0, 0, 0, 0, 0};
    if (c8 < 128) {
        int e  = c8 >> 5;
        int d0 = (c8 & 31) << 3;
        const float* s = (o_ < HDIM)
            ? Whid + ((size_t)e * HDIM + o_) * D_IN + d0
            : Wres + ((size_t)e * ODIM + (o_ - HDIM)) * D_IN + d0;
#pragma unroll
        for (int j = 0; j < 8; ++j) v[j] = f2b(s[j]);
    } else if (c8 == 128) {
#pragma unroll
        for (int j = 0; j < 4; ++j) {
            float b = (o_ < HDIM) ? bhid[j * HDIM + o_] : bres[j * ODIM + (o_ - HDIM)];
            v[j] = f2b(b);
        }
    }
    *(uint4*)(Bp + (size_t)o_ * KPACK + c8 * 8) = *(const uint4*)v;
}

// ---- K0g: W_out f32 -> bf16 -------------------------------------------------
__global__ __launch_bounds__(256) void k_pack_wout(
    const float* __restrict__ Wout, ushort* __restrict__ Wb) {
    int gid = blockIdx.x * 256 + threadIdx.x;   // 768*128 items
    const float* s = Wout + (size_t)gid * 8;
    ushort v[8] __attribute__((aligned(16)));
#pragma unroll
    for (int j = 0; j < 8; ++j) v[j] = f2b(s[j]);
    *(uint4*)(Wb + (size_t)gid * 8) = *(const uint4*)v;
}

// ---- GEMM1: class-sparse 256^2, dynamic K-tile list, 8-phase pipeline ------
__global__ __launch_bounds__(512, 2) void k_gemm1(
    const ushort* __restrict__ A, const ushort* __restrict__ B,
    const int* __restrict__ pbase, const int* __restrict__ cnt,
    const int* __restrict__ tokof,
    ushort* __restrict__ hidB, ushort* __restrict__ resb) {
    __shared__ __align__(16) ushort As[2][256 * 64];
    __shared__ __align__(16) ushort Bs[2][256 * 64];
    __shared__ int kcs_s[16];
    __shared__ int nt_s;
    const int tid = threadIdx.x;
    const int lane = tid & 63, w = tid >> 6;
    const int wr = w >> 2, wc = w & 3;
    const int r = lane & 15, g = lane >> 4;
    const int sx = r & 7;

    // bijective XCD swizzle for 301 blocks (q=37, rem=5)
    int bid = blockIdx.x;
    int xcd = bid & 7, jj = bid >> 3;
    const int q = G1BLK / 8, rm = G1BLK % 8;
    int widx = (xcd < rm ? xcd * (q + 1) : rm * (q + 1) + (xcd - rm) * q) + jj;
    int bm = widx / 7, bn = widx - bm * 7;

    if (tid == 0) {
        const int cm[NCLS] = {12, 10, 9, 6, 5, 3, 8, 4, 2, 1, 0};
        int start = bm * 256;
        unsigned um = 0;
        for (int k = 0; k < NCLS; ++k)
            if (start >= pbase[k] && start < pbase[k] + cnt[k]) um = cm[k];
        int m = 0, lst[16];
        for (int e = 0; e < 4; ++e)
            if ((um >> e) & 1) {
                lst[m++] = 4 * e;
                if (e >= 2) lst[m++] = 4 * e + 1;
                lst[m++] = 4 * e + 2;
                if (e >= 2) lst[m++] = 4 * e + 3;
            }
        if (m == 0) lst[m++] = 0;
        lst[m++] = 16;                     // bias tile
        nt_s = m;
        for (int k = 0; k < m; ++k) kcs_s[k] = lst[k] * 8;   // chunk offsets
    }
    __syncthreads();
    const int nt = nt_s;

    const int srow = tid >> 3;                  // 0..63
    const int gc   = (tid & 7) ^ (srow & 7);
    const int wv8  = w * 8;
    const ushort* Abase = A + (size_t)(bm * 256) * KPACK;
    const ushort* Bbase = B + (size_t)(bn * 256) * KPACK;

#define STG(gsrc, grow, kc, lds, lrow)                                      \
    stage16((gsrc) + (size_t)((grow) + srow) * KPACK + ((kc) + gc) * 8,     \
            (lds) + ((lrow) + wv8) * 64)

    {
        const int t0c = kcs_s[0], t1c = kcs_s[1];
        STG(Bbase, 0, t0c, &Bs[0][0], 0);     STG(Bbase, 64, t0c, &Bs[0][0], 64);
        STG(Bbase, 128, t0c, &Bs[0][0], 128); STG(Bbase, 192, t0c, &Bs[0][0], 192);
        STG(Abase, 0, t0c, &As[0][0], 0);     STG(Abase, 64, t0c, &As[0][0], 64);
        STG(Abase, 128, t0c, &As[0][0], 128); STG(Abase, 192, t0c, &As[0][0], 192);
        STG(Bbase, 0, t1c, &Bs[1][0], 0);     STG(Bbase, 64, t1c, &Bs[1][0], 64);
        STG(Bbase, 128, t1c, &Bs[1][0], 128); STG(Bbase, 192, t1c, &Bs[1][0], 192);
        STG(Abase, 0, t1c, &As[1][0], 0);     STG(Abase, 128, t1c, &As[1][0], 128);
    }
    asm volatile("s_waitcnt vmcnt(6)" ::: "memory");
    __builtin_amdgcn_s_barrier();

    f32x4 acc[8][4] = {};
    bf16x8 af[2][2], bfr[4][2];

#define LD_A(buf, mi, ks) (*(const bf16x8*)&As[buf][(wr * 128 + (mi) * 16 + r) * 64 + ((((ks) * 4 + g) ^ sx) * 8)])
#define LD_B(buf, j, ks)  (*(const bf16x8*)&Bs[buf][(wc * 64  + (j) * 16 + r) * 64 + ((((ks) * 4 + g) ^ sx) * 8)])
#define READ_A(buf, qq) do {                                                  \
    af[0][0] = LD_A(buf, 2 * (qq), 0);     af[0][1] = LD_A(buf, 2 * (qq), 1); \
    af[1][0] = LD_A(buf, 2 * (qq) + 1, 0); af[1][1] = LD_A(buf, 2 * (qq) + 1, 1); } while (0)
#define READ_B(buf) do { _Pragma("unroll")                                   \
    for (int j_ = 0; j_ < 4; ++j_) { bfr[j_][0] = LD_B(buf, j_, 0); bfr[j_][1] = LD_B(buf, j_, 1); } } while (0)
#define MFMA_Q(qq) do {                                                      \
    __builtin_amdgcn_s_setprio(1);                                           \
    _Pragma("unroll") for (int i_ = 0; i_ < 2; ++i_)                         \
    _Pragma("unroll") for (int k_ = 0; k_ < 2; ++k_)                         \
    _Pragma("unroll") for (int j_ = 0; j_ < 4; ++j_)                         \
        acc[2 * (qq) + i_][j_] = __builtin_amdgcn_mfma_f32_16x16x32_bf16(    \
            af[i_][k_], bfr[j_][k_], acc[2 * (qq) + i_][j_], 0, 0, 0);       \
    __builtin_amdgcn_s_setprio(0); } while (0)
#define OPEN_BAR() do { __builtin_amdgcn_sched_barrier(0);                   \
    __builtin_amdgcn_s_barrier(); } while (0)

    const int H = nt >> 1;
    for (int i = 0; i < H; ++i) {
        const int kcp = kcs_s[2 * i + 1];
        const bool has2 = (2 * i + 2) < nt;
        const bool has3 = (2 * i + 3) < nt;
        const int kc0 = kcs_s[2 * i + 2];   // valid only if has2
        const int kc1 = kcs_s[2 * i + 3];   // valid only if has3
        // p1: read buf0 {B, Aq0}; stage buf1.A S1,S3 (tile 2i+1)
        READ_B(0); READ_A(0, 0);
        STG(Abase, 64, kcp, &As[1][0], 64);
        STG(Abase, 192, kcp, &As[1][0], 192);
        OPEN_BAR(); MFMA_Q(0); __builtin_amdgcn_s_barrier();
        // p2
        READ_A(0, 1);
        if (has2) { STG(Bbase, 0, kc0, &Bs[0][0], 0);
                    STG(Bbase, 64, kc0, &Bs[0][0], 64); }
        OPEN_BAR(); MFMA_Q(1);
        // p3
        READ_A(0, 2);
        if (has2) { STG(Bbase, 128, kc0, &Bs[0][0], 128);
                    STG(Bbase, 192, kc0, &Bs[0][0], 192); }
        OPEN_BAR(); MFMA_Q(2);
        // p4 + publish buf1
        READ_A(0, 3);
        if (has2) { STG(Abase, 0, kc0, &As[0][0], 0);
                    STG(Abase, 128, kc0, &As[0][0], 128); }
        OPEN_BAR(); MFMA_Q(3);
        if (has2) asm volatile("s_waitcnt vmcnt(6)" ::: "memory");
        else      asm volatile("s_waitcnt vmcnt(0)" ::: "memory");
        __builtin_amdgcn_s_barrier();
        // p5: read buf1 {B, Aq0}; stage buf0.A S1,S3
        READ_B(1); READ_A(1, 0);
        if (has2) { STG(Abase, 64, kc0, &As[0][0], 64);
                    STG(Abase, 192, kc0, &As[0][0], 192); }
        OPEN_BAR(); MFMA_Q(0); __builtin_amdgcn_s_barrier();
        // p6
        READ_A(1, 1);
        if (has3) { STG(Bbase, 0, kc1, &Bs[1][0], 0);
                    STG(Bbase, 64, kc1, &Bs[1][0], 64); }
        OPEN_BAR(); MFMA_Q(1);
        // p7
        READ_A(1, 2);
        if (has3) { STG(Bbase, 128, kc1, &Bs[1][0], 128);
                    STG(Bbase, 192, kc1, &Bs[1][0], 192); }
        OPEN_BAR(); MFMA_Q(2);
        // p8 + publish buf0 (only if a next tile exists)
        READ_A(1, 3);
        if (has3) { STG(Abase, 0, kc1, &As[1][0], 0);
                    STG(Abase, 128, kc1, &As[1][0], 128); }
        OPEN_BAR(); MFMA_Q(3);
        if (has2) {
            if (has3) asm volatile("s_waitcnt vmcnt(6)" ::: "memory");
            else      asm volatile("s_waitcnt vmcnt(0)" ::: "memory");
            __builtin_amdgcn_s_barrier();
        }
    }
    if (nt & 1) {   // tail tile from buf0 (published with full drain)
        READ_B(0); READ_A(0, 0); MFMA_Q(0);
        READ_A(0, 1); MFMA_Q(1);
        READ_A(0, 2); MFMA_Q(2);
        READ_A(0, 3); MFMA_Q(3);
    }
#undef STG
#undef LD_A
#undef LD_B
#undef READ_A
#undef READ_B
#undef MFMA_Q
#undef OPEN_BAR

#pragma unroll
    for (int fi = 0; fi < 8; ++fi) {
#pragma unroll
        for (int qq = 0; qq < 4; ++qq) {
            int row = bm * 256 + wr * 128 + fi * 16 + g * 4 + qq;
            int tk = tokof[row];
            if (tk < 0) continue;
#pragma unroll
            for (int j = 0; j < 4; ++j) {
                int col = bn * 256 + wc * 64 + j * 16 + r;
                float v = acc[fi][j][qq];
                if (col < HDIM) {
                    hidB[(size_t)tk * HDIM + col] = f2b(gelu_f(v));
                } else {
                    resb[(size_t)tk * ODIM + (col - HDIM)] = f2b(v);
                }
            }
        }
    }
}

// ---- GEMM2: 128^2 tile, BK=64, 2-deep counted pipeline; bf16 res/out -------
__global__ __launch_bounds__(256, 2) void k_gemm2(
    const ushort* __restrict__ A, const ushort* __restrict__ B,
    const float* __restrict__ bout, const ushort* __restrict__ resb,
    ushort* __restrict__ outb) {
    __shared__ __align__(16) ushort As[2][128 * 64];
    __shared__ __align__(16) ushort Bs[2][128 * 64];
    const int tid = threadIdx.x;
    const int lane = tid & 63, w = tid >> 6;
    const int wr = w >> 1, wc = w & 1;
    const int r = lane & 15, g = lane >> 4;
    const int bm = blockIdx.x, bn = blockIdx.y;

    const int srow = tid >> 3;
    const int gc   = (tid & 7) ^ (srow & 7);
    const ushort* Ag = A + (size_t)(bm * 128 + srow) * HDIM + gc * 8;
    const ushort* Bg = B + (size_t)(bn * 128 + srow) * HDIM + gc * 8;
    const int ldst = (w * 8) * 64;

#define G2_STAGE(p, kt) do {                                            \
    _Pragma("unroll")                                                   \
    for (int i_ = 0; i_ < 4; ++i_) {                                    \
        stage16(Ag + (size_t)(i_ * 32) * HDIM + (kt), &As[p][ldst + i_ * 32 * 64]); \
        stage16(Bg + (size_t)(i_ * 32) * HDIM + (kt), &Bs[p][ldst + i_ * 32 * 64]); \
    } } while (0)

    G2_STAGE(0, 0);
    G2_STAGE(1, 64);

    f32x4 acc[4][4] = {};
    const int cA = (wr * 64 + r) * 64;
    const int cB = (wc * 64 + r) * 64;
    const int sx = r & 7;

    int cur = 0;
    for (int t = 0; t < 16; ++t) {
        if (t < 15) asm volatile("s_waitcnt vmcnt(8)" ::: "memory");
        else        asm volatile("s_waitcnt vmcnt(0)" ::: "memory");
        __builtin_amdgcn_s_barrier();
        const ushort* Ab = As[cur];
        const ushort* Bb = Bs[cur];
#pragma unroll
        for (int kh = 0; kh < 2; ++kh) {
            const int cs = ((kh * 4 + g) ^ sx) * 8;
            bf16x8 bfr[4], af[4];
#pragma unroll
            for (int j = 0; j < 4; ++j)
                bfr[j] = *(const bf16x8*)&Bb[cB + j * 16 * 64 + cs];
#pragma unroll
            for (int i = 0; i < 4; ++i)
                af[i] = *(const bf16x8*)&Ab[cA + i * 16 * 64 + cs];
            __builtin_amdgcn_s_setprio(1);
#pragma unroll
            for (int i = 0; i < 4; ++i)
#pragma unroll
                for (int j = 0; j < 4; ++j)
                    acc[i][j] = __builtin_amdgcn_mfma_f32_16x16x32_bf16(
                        af[i], bfr[j], acc[i][j], 0, 0, 0);
            __builtin_amdgcn_s_setprio(0);
        }
        asm volatile("s_waitcnt lgkmcnt(0)" ::: "memory");
        __builtin_amdgcn_s_barrier();
        if (t + 2 < 16) G2_STAGE(cur, (t + 2) * 64);
        cur ^= 1;
    }
#undef G2_STAGE

#pragma unroll
    for (int fi = 0; fi < 4; ++fi) {
#pragma unroll
        for (int j = 0; j < 4; ++j) {
            int col = bn * 128 + wc * 64 + j * 16 + r;
#pragma unroll
            for (int qq = 0; qq < 4; ++qq) {
                int row = bm * 128 + wr * 64 + fi * 16 + g * 4 + qq;
                size_t idx = (size_t)row * ODIM + col;
                float v = acc[fi][j][qq] + bout[col] + b2f(resb[idx]);
                outb[idx] = f2b(v);
            }
        }
    }
}

// ---- RMS norm row-wise (bf16 in, f32 out) ----------------------------------
__global__ __launch_bounds__(256) void k_rms(
    const ushort* __restrict__ outb, const float* __restrict__ lnw,
    float* __restrict__ out) {
    int row = blockIdx.x, t = threadIdx.x;
    const ushort* p = outb + (size_t)row * ODIM;
    float v0 = b2f(p[t]), v1 = b2f(p[t + 256]), v2 = b2f(p[t + 512]);
    float s = v0 * v0 + v1 * v1 + v2 * v2;
#pragma unroll
    for (int off = 32; off > 0; off >>= 1) s += __shfl_down(s, off, 64);
    __shared__ float ws4[4];
    if ((t & 63) == 0) ws4[t >> 6] = s;
    __syncthreads();
    float tot = ws4[0] + ws4[1] + ws4[2] + ws4[3];
    float sc = rsqrtf(tot * (1.f / 768.f) + 1e-6f);
    out[(size_t)row * ODIM + t]       = lnw[t]       * v0 * sc;
    out[(size_t)row * ODIM + t + 256] = lnw[t + 256] * v1 * sc;
    out[(size_t)row * ODIM + t + 512] = lnw[t + 512] * v2 * sc;
}

extern "C" void kernel_launch(void* const* d_in, const int* in_sizes, int n_in,
                              void* d_out, int out_size, void* d_ws, size_t ws_size,
                              hipStream_t stream) {
    const float* ew   = (const float*)d_in[2];
    const int*   ei   = (const int*)d_in[3];
    const float* xf   = (const float*)d_in[4];
    const float* Whid = (const float*)d_in[5];
    const float* bhid = (const float*)d_in[6];
    const float* Wout = (const float*)d_in[7];
    const float* bout = (const float*)d_in[8];
    const float* Wres = (const float*)d_in[9];
    const float* bres = (const float*)d_in[10];
    const float* lnw  = (const float*)d_in[11];

    char* ws = (char*)d_ws;
    float* wmap    = (float*)(ws);                   // 131072
    int*   classid = (int*)(ws + 131072);            // 32768
    int*   bhist   = (int*)(ws + 163840);            // 2048
    int*   pbase   = (int*)(ws + 165888);            // 64
    int*   cnt     = (int*)(ws + 165952);            // 64
    int*   cursor  = (int*)(ws + 166016);            // 128
    int*   sortpos = (int*)(ws + 166144);            // 32768
    int*   tokof   = (int*)(ws + 198912);            // 44032
    ushort* Ap     = (ushort*)(ws + 242944);         // 11008*1088*2 = 23953408
    ushort* Bp     = (ushort*)(ws + 24196352);       // 1792*1088*2  = 3899392
    ushort* Wb     = (ushort*)(ws + 28095744);       // 768*1024*2   = 1572864
    ushort* hidB   = (ushort*)(ws + 29668608);       // 8192*1024*2  = 16777216
    ushort* resb   = (ushort*)(ws + 46445824);       // 8192*768*2   = 12582912
    ushort* outb   = (ushort*)(ws + 242944);         // alias Ap (dead after gemm1)

    k_route<<<32, 256, 0, stream>>>(ew, ei, wmap, classid, bhist);
    k_init<<<MTILES, 256, 0, stream>>>(tokof);
    k_scan<<<1, 64, 0, stream>>>(bhist, pbase, cnt, cursor);
    k_scatter<<<32, 256, 0, stream>>>(classid, cursor, sortpos, tokof);
    k_pack_a<<<4352, 256, 0, stream>>>(xf, wmap, sortpos, Ap);
    k_pack_b<<<952, 256, 0, stream>>>(Whid, bhid, Wres, bres, Bp);
    k_pack_wout<<<384, 256, 0, stream>>>(Wout, Wb);
    k_gemm1<<<G1BLK, 512, 0, stream>>>(Ap, Bp, pbase, cnt, tokof, hidB, resb);
    k_gemm2<<<dim3(64, 6), 256, 0, stream>>>(hidB, Wb, bout, resb, outb);
    k_rms<<<8192, 256, 0, stream>>>(outb, lnw, (float*)d_out);
}

// Round 9
// 84.223 us; speedup vs baseline: 1.7473x; 1.7473x over previous
//
#include <hip/hip_runtime.h>
#include <hip/hip_bf16.h>

#define TOKENS 8192
#define D_IN   256
#define HDIM   1024
#define ODIM   768
#define KPACK  704    // 640 statically-valid cols + bias chunk + pad -> 11 x BK=64
#define NCHUNK 88     // KPACK/8
#define NKT    11     // K tiles

typedef short bf16x8 __attribute__((ext_vector_type(8)));
typedef float f32x4  __attribute__((ext_vector_type(4)));

static __device__ __forceinline__ ushort f2b(float f) {
    union { __hip_bfloat16 b; ushort u; } cv;
    cv.b = __float2bfloat16(f);
    return cv.u;
}
static __device__ __forceinline__ float b2f(ushort u) {
    union { ushort u; __hip_bfloat16 b; } cv;
    cv.u = u;
    return __bfloat162float(cv.b);
}

// packed chunk index (0..79) -> (expert, source col d0); static masks:
// e0: cols [0,32)u[128,160) = 8 chunks; e1: 16; e2: 24; e3: 32 chunks
static __device__ __forceinline__ void chunk_map(int c8, int& e, int& d0) {
    int cc;
    if (c8 < 8)       { e = 0; cc = c8; }
    else if (c8 < 24) { e = 1; cc = c8 - 8; }
    else if (c8 < 48) { e = 2; cc = c8 - 24; }
    else              { e = 3; cc = c8 - 48; }
    int half = 4 * (e + 1);
    d0 = (cc < half) ? cc * 8 : 128 + (cc - half) * 8;
}

// direct global->LDS DMA, 16B/lane; LDS dest = wave-uniform base + lane*16
static __device__ __forceinline__ void stage16(const ushort* g, ushort* l) {
    __builtin_amdgcn_global_load_lds(
        (const __attribute__((address_space(1))) void*)g,
        (__attribute__((address_space(3))) void*)l, 16, 0, 0);
}

// tanh-form GELU (max dev from exact erf-GELU ~3e-4)
static __device__ __forceinline__ float gelu_f(float v) {
    float y = 0.7978845608f * v * (1.f + 0.044715f * v * v);
    return v - v / (__expf(2.f * y) + 1.f);
}

// ---- K0a: per-(expert,token) combine weight --------------------------------
__global__ __launch_bounds__(256) void k_route(
    const float* __restrict__ ew, const int* __restrict__ ei,
    float* __restrict__ wmap) {
    int n = blockIdx.x * 256 + threadIdx.x;
    if (n >= TOKENS) return;
    int   i0 = ei[2 * n], i1 = ei[2 * n + 1];
    float w0 = ew[2 * n], w1 = ew[2 * n + 1];
    bool v0 = (unsigned)i0 < 4u, v1 = (unsigned)i1 < 4u;
    float rs = (v0 ? w0 : 0.f) + (v1 ? w1 : 0.f);
    if (rs == 0.f) rs = 1.f;
    float o0 = v0 ? w0 / rs : 0.f;
    float o1 = v1 ? w1 / rs : 0.f;
#pragma unroll
    for (int e = 0; e < 4; ++e) {
        float m = 0.f;
        if (v0 && i0 == e) m += o0;
        if (v1 && i1 == e) m += o1;
        wmap[e * TOKENS + n] = m;
    }
}

// ---- K0b: pack A'' (bf16, static-compressed cols, K=704) -------------------
__global__ __launch_bounds__(256) void k_pack_a(
    const float* __restrict__ xf, const float* __restrict__ wmap,
    ushort* __restrict__ Ap) {
    int gid = blockIdx.x * 256 + threadIdx.x;   // 8192*88 items
    int n  = gid / NCHUNK;
    int c8 = gid - n * NCHUNK;
    ushort o[8] __attribute__((aligned(16))) = {0, 0, 0, 0, 0, 0, 0, 0};
    if (c8 < 80) {
        int e, d0;
        chunk_map(c8, e, d0);
        float w = wmap[e * TOKENS + n];
        if (w != 0.f) {
            const float* s = xf + ((size_t)e * TOKENS + n) * D_IN + d0;
#pragma unroll
            for (int j = 0; j < 8; ++j) {
                float v = s[j];
                if (!(v == v)) v = 0.f;   // nan_to_num
                o[j] = f2b(w * v);
            }
        }
    } else if (c8 == 80) {
#pragma unroll
        for (int j = 0; j < 4; ++j) o[j] = f2b(wmap[j * TOKENS + n]);
    }
    *(uint4*)(Ap + (size_t)n * KPACK + c8 * 8) = *(const uint4*)o;
}

// ---- K0c: pack B'' = [W_hid;W_res] compressed cols, bias chunk 80 ----------
__global__ __launch_bounds__(256) void k_pack_b(
    const float* __restrict__ Whid, const float* __restrict__ bhid,
    const float* __restrict__ Wres, const float* __restrict__ bres,
    ushort* __restrict__ Bp) {
    int gid = blockIdx.x * 256 + threadIdx.x;   // 1792*88 items
    int o_ = gid / NCHUNK;
    int c8 = gid - o_ * NCHUNK;
    ushort v[8] __attribute__((aligned(16))) = {0, 0, 0, 0, 0, 0, 0, 0};
    if (c8 < 80) {
        int e, d0;
        chunk_map(c8, e, d0);
        const float* s = (o_ < HDIM)
            ? Whid + ((size_t)e * HDIM + o_) * D_IN + d0
            : Wres + ((size_t)e * ODIM + (o_ - HDIM)) * D_IN + d0;
#pragma unroll
        for (int j = 0; j < 8; ++j) v[j] = f2b(s[j]);
    } else if (c8 == 80) {
#pragma unroll
        for (int j = 0; j < 4; ++j) {
            float b = (o_ < HDIM) ? bhid[j * HDIM + o_] : bres[j * ODIM + (o_ - HDIM)];
            v[j] = f2b(b);
        }
    }
    *(uint4*)(Bp + (size_t)o_ * KPACK + c8 * 8) = *(const uint4*)v;
}

// ---- K0d: W_out f32 -> bf16 -------------------------------------------------
__global__ __launch_bounds__(256) void k_pack_wout(
    const float* __restrict__ Wout, ushort* __restrict__ Wb) {
    int gid = blockIdx.x * 256 + threadIdx.x;   // 768*128 items
    const float* s = Wout + (size_t)gid * 8;
    ushort v[8] __attribute__((aligned(16)));
#pragma unroll
    for (int j = 0; j < 8; ++j) v[j] = f2b(s[j]);
    *(uint4*)(Wb + (size_t)gid * 8) = *(const uint4*)v;
}

// ---- GEMM1: 256^2, K=704 (11 tiles), 8-phase counted-vmcnt, static unroll --
__global__ __launch_bounds__(512, 2) void k_gemm1(
    const ushort* __restrict__ A, const ushort* __restrict__ B,
    ushort* __restrict__ hidB, ushort* __restrict__ resb) {
    __shared__ __align__(16) ushort As[2][256 * 64];   // 32KB each
    __shared__ __align__(16) ushort Bs[2][256 * 64];
    const int tid = threadIdx.x;
    const int lane = tid & 63, w = tid >> 6;
    const int wr = w >> 2, wc = w & 3;          // 2M x 4N wave grid
    const int r = lane & 15, g = lane >> 4;
    const int sx = r & 7;

    // XCD-bijective block swizzle: 224 blocks = 8 XCD x 28
    int bid  = blockIdx.x;
    int widx = (bid & 7) * 28 + (bid >> 3);
    int bm = widx / 7, bn = widx - bm * 7;

    const int srow = tid >> 3;                  // 0..63
    const int gc   = (tid & 7) ^ (srow & 7);
    const int wv8  = w * 8;
    const ushort* Abase = A + (size_t)(bm * 256) * KPACK;
    const ushort* Bbase = B + (size_t)(bn * 256) * KPACK;

#define STG(gsrc, grow, kc, lds, lrow)                                      \
    stage16((gsrc) + (size_t)((grow) + srow) * KPACK + ((kc) + gc) * 8,     \
            (lds) + ((lrow) + wv8) * 64)

    // prologue: tile0 -> buf0 full (8 calls); tile1 -> buf1 B + A.S0,S2 (6)
    STG(Bbase, 0, 0, &Bs[0][0], 0);     STG(Bbase, 64, 0, &Bs[0][0], 64);
    STG(Bbase, 128, 0, &Bs[0][0], 128); STG(Bbase, 192, 0, &Bs[0][0], 192);
    STG(Abase, 0, 0, &As[0][0], 0);     STG(Abase, 64, 0, &As[0][0], 64);
    STG(Abase, 128, 0, &As[0][0], 128); STG(Abase, 192, 0, &As[0][0], 192);
    STG(Bbase, 0, 8, &Bs[1][0], 0);     STG(Bbase, 64, 8, &Bs[1][0], 64);
    STG(Bbase, 128, 8, &Bs[1][0], 128); STG(Bbase, 192, 8, &Bs[1][0], 192);
    STG(Abase, 0, 8, &As[1][0], 0);     STG(Abase, 128, 8, &As[1][0], 128);
    asm volatile("s_waitcnt vmcnt(6)" ::: "memory");
    __builtin_amdgcn_s_barrier();

    f32x4 acc[8][4] = {};
    bf16x8 af[2][2], bfr[4][2];

#define LD_A(buf, mi, ks) (*(const bf16x8*)&As[buf][(wr * 128 + (mi) * 16 + r) * 64 + ((((ks) * 4 + g) ^ sx) * 8)])
#define LD_B(buf, j, ks)  (*(const bf16x8*)&Bs[buf][(wc * 64  + (j) * 16 + r) * 64 + ((((ks) * 4 + g) ^ sx) * 8)])
#define READ_A(buf, qq) do {                                                  \
    af[0][0] = LD_A(buf, 2 * (qq), 0);     af[0][1] = LD_A(buf, 2 * (qq), 1); \
    af[1][0] = LD_A(buf, 2 * (qq) + 1, 0); af[1][1] = LD_A(buf, 2 * (qq) + 1, 1); } while (0)
#define READ_B(buf) do { _Pragma("unroll")                                   \
    for (int j_ = 0; j_ < 4; ++j_) { bfr[j_][0] = LD_B(buf, j_, 0); bfr[j_][1] = LD_B(buf, j_, 1); } } while (0)
#define MFMA_Q(qq) do {                                                      \
    __builtin_amdgcn_s_setprio(1);                                           \
    _Pragma("unroll") for (int i_ = 0; i_ < 2; ++i_)                         \
    _Pragma("unroll") for (int k_ = 0; k_ < 2; ++k_)                         \
    _Pragma("unroll") for (int j_ = 0; j_ < 4; ++j_)                         \
        acc[2 * (qq) + i_][j_] = __builtin_amdgcn_mfma_f32_16x16x32_bf16(    \
            af[i_][k_], bfr[j_][k_], acc[2 * (qq) + i_][j_], 0, 0, 0);       \
    __builtin_amdgcn_s_setprio(0); } while (0)
#define OPEN_BAR() do { __builtin_amdgcn_sched_barrier(0);                   \
    __builtin_amdgcn_s_barrier(); } while (0)

#pragma unroll
    for (int i = 0; i < 5; ++i) {               // 2 tiles/iter; tiles 0..9
        const int kcp = (2 * i + 1) * 8;        // tile 2i+1 -> buf1 A S1,S3
        const int kc0 = (2 * i + 2) * 8;        // tile 2i+2 -> buf0 (always <11)
        const int kc1 = (2 * i + 3) * 8;        // tile 2i+3 -> buf1 (if st1)
        const bool st1 = (i < 4);
        // p1: read buf0 {B, Aq0}; stage buf1.A S1,S3
        READ_B(0); READ_A(0, 0);
        STG(Abase, 64, kcp, &As[1][0], 64);
        STG(Abase, 192, kcp, &As[1][0], 192);
        OPEN_BAR(); MFMA_Q(0); __builtin_amdgcn_s_barrier();
        // p2
        READ_A(0, 1);
        STG(Bbase, 0, kc0, &Bs[0][0], 0);
        STG(Bbase, 64, kc0, &Bs[0][0], 64);
        OPEN_BAR(); MFMA_Q(1);
        // p3
        READ_A(0, 2);
        STG(Bbase, 128, kc0, &Bs[0][0], 128);
        STG(Bbase, 192, kc0, &Bs[0][0], 192);
        OPEN_BAR(); MFMA_Q(2);
        // p4 + publish buf1 (vmcnt(6) = p2..p4's 6 stages may fly)
        READ_A(0, 3);
        STG(Abase, 0, kc0, &As[0][0], 0);
        STG(Abase, 128, kc0, &As[0][0], 128);
        OPEN_BAR(); MFMA_Q(3);
        asm volatile("s_waitcnt vmcnt(6)" ::: "memory");
        __builtin_amdgcn_s_barrier();
        // p5: read buf1 {B, Aq0}; stage buf0.A S1,S3
        READ_B(1); READ_A(1, 0);
        STG(Abase, 64, kc0, &As[0][0], 64);
        STG(Abase, 192, kc0, &As[0][0], 192);
        OPEN_BAR(); MFMA_Q(0); __builtin_amdgcn_s_barrier();
        // p6
        READ_A(1, 1);
        if (st1) { STG(Bbase, 0, kc1, &Bs[1][0], 0);
                   STG(Bbase, 64, kc1, &Bs[1][0], 64); }
        OPEN_BAR(); MFMA_Q(1);
        // p7
        READ_A(1, 2);
        if (st1) { STG(Bbase, 128, kc1, &Bs[1][0], 128);
                   STG(Bbase, 192, kc1, &Bs[1][0], 192); }
        OPEN_BAR(); MFMA_Q(2);
        // p8 + publish buf0 (drain fully before tail on last iter)
        READ_A(1, 3);
        if (st1) { STG(Abase, 0, kc1, &As[1][0], 0);
                   STG(Abase, 128, kc1, &As[1][0], 128); }
        OPEN_BAR(); MFMA_Q(3);
        if (st1) asm volatile("s_waitcnt vmcnt(6)" ::: "memory");
        else     asm volatile("s_waitcnt vmcnt(0)" ::: "memory");
        __builtin_amdgcn_s_barrier();
    }
    // tail: tile 10 from buf0 (fully drained); no concurrent writers
    READ_B(0); READ_A(0, 0); MFMA_Q(0);
    READ_A(0, 1); MFMA_Q(1);
    READ_A(0, 2); MFMA_Q(2);
    READ_A(0, 3); MFMA_Q(3);
#undef STG
#undef LD_A
#undef LD_B
#undef READ_A
#undef READ_B
#undef MFMA_Q
#undef OPEN_BAR

#pragma unroll
    for (int fi = 0; fi < 8; ++fi) {
#pragma unroll
        for (int j = 0; j < 4; ++j) {
            int col = bn * 256 + wc * 64 + j * 16 + r;
#pragma unroll
            for (int qq = 0; qq < 4; ++qq) {
                int row = bm * 256 + wr * 128 + fi * 16 + g * 4 + qq;
                float v = acc[fi][j][qq];
                if (col < HDIM) {
                    hidB[(size_t)row * HDIM + col] = f2b(gelu_f(v));
                } else {
                    resb[(size_t)row * ODIM + (col - HDIM)] = f2b(v);
                }
            }
        }
    }
}

// ---- GEMM2: 128^2 tile, BK=64, 2-deep counted pipeline; bf16 res/out -------
__global__ __launch_bounds__(256, 2) void k_gemm2(
    const ushort* __restrict__ A, const ushort* __restrict__ B,
    const float* __restrict__ bout, const ushort* __restrict__ resb,
    ushort* __restrict__ outb) {
    __shared__ __align__(16) ushort As[2][128 * 64];
    __shared__ __align__(16) ushort Bs[2][128 * 64];
    const int tid = threadIdx.x;
    const int lane = tid & 63, w = tid >> 6;
    const int wr = w >> 1, wc = w & 1;
    const int r = lane & 15, g = lane >> 4;
    const int bm = blockIdx.x, bn = blockIdx.y;

    const int srow = tid >> 3;
    const int gc   = (tid & 7) ^ (srow & 7);
    const ushort* Ag = A + (size_t)(bm * 128 + srow) * HDIM + gc * 8;
    const ushort* Bg = B + (size_t)(bn * 128 + srow) * HDIM + gc * 8;
    const int ldst = (w * 8) * 64;

#define G2_STAGE(p, kt) do {                                            \
    _Pragma("unroll")                                                   \
    for (int i_ = 0; i_ < 4; ++i_) {                                    \
        stage16(Ag + (size_t)(i_ * 32) * HDIM + (kt), &As[p][ldst + i_ * 32 * 64]); \
        stage16(Bg + (size_t)(i_ * 32) * HDIM + (kt), &Bs[p][ldst + i_ * 32 * 64]); \
    } } while (0)

    G2_STAGE(0, 0);
    G2_STAGE(1, 64);

    f32x4 acc[4][4] = {};
    const int cA = (wr * 64 + r) * 64;
    const int cB = (wc * 64 + r) * 64;
    const int sx = r & 7;

    int cur = 0;
    for (int t = 0; t < 16; ++t) {
        if (t < 15) asm volatile("s_waitcnt vmcnt(8)" ::: "memory");
        else        asm volatile("s_waitcnt vmcnt(0)" ::: "memory");
        __builtin_amdgcn_s_barrier();
        const ushort* Ab = As[cur];
        const ushort* Bb = Bs[cur];
#pragma unroll
        for (int kh = 0; kh < 2; ++kh) {
            const int cs = ((kh * 4 + g) ^ sx) * 8;
            bf16x8 bfr[4], af[4];
#pragma unroll
            for (int j = 0; j < 4; ++j)
                bfr[j] = *(const bf16x8*)&Bb[cB + j * 16 * 64 + cs];
#pragma unroll
            for (int i = 0; i < 4; ++i)
                af[i] = *(const bf16x8*)&Ab[cA + i * 16 * 64 + cs];
            __builtin_amdgcn_s_setprio(1);
#pragma unroll
            for (int i = 0; i < 4; ++i)
#pragma unroll
                for (int j = 0; j < 4; ++j)
                    acc[i][j] = __builtin_amdgcn_mfma_f32_16x16x32_bf16(
                        af[i], bfr[j], acc[i][j], 0, 0, 0);
            __builtin_amdgcn_s_setprio(0);
        }
        asm volatile("s_waitcnt lgkmcnt(0)" ::: "memory");
        __builtin_amdgcn_s_barrier();
        if (t + 2 < 16) G2_STAGE(cur, (t + 2) * 64);
        cur ^= 1;
    }
#undef G2_STAGE

#pragma unroll
    for (int fi = 0; fi < 4; ++fi) {
#pragma unroll
        for (int j = 0; j < 4; ++j) {
            int col = bn * 128 + wc * 64 + j * 16 + r;
#pragma unroll
            for (int qq = 0; qq < 4; ++qq) {
                int row = bm * 128 + wr * 64 + fi * 16 + g * 4 + qq;
                size_t idx = (size_t)row * ODIM + col;
                float v = acc[fi][j][qq] + bout[col] + b2f(resb[idx]);
                outb[idx] = f2b(v);
            }
        }
    }
}

// ---- RMS norm row-wise (bf16 in, f32 out) ----------------------------------
__global__ __launch_bounds__(256) void k_rms(
    const ushort* __restrict__ outb, const float* __restrict__ lnw,
    float* __restrict__ out) {
    int row = blockIdx.x, t = threadIdx.x;
    const ushort* p = outb + (size_t)row * ODIM;
    float v0 = b2f(p[t]), v1 = b2f(p[t + 256]), v2 = b2f(p[t + 512]);
    float s = v0 * v0 + v1 * v1 + v2 * v2;
#pragma unroll
    for (int off = 32; off > 0; off >>= 1) s += __shfl_down(s, off, 64);
    __shared__ float ws4[4];
    if ((t & 63) == 0) ws4[t >> 6] = s;
    __syncthreads();
    float tot = ws4[0] + ws4[1] + ws4[2] + ws4[3];
    float sc = rsqrtf(tot * (1.f / 768.f) + 1e-6f);
    out[(size_t)row * ODIM + t]       = lnw[t]       * v0 * sc;
    out[(size_t)row * ODIM + t + 256] = lnw[t + 256] * v1 * sc;
    out[(size_t)row * ODIM + t + 512] = lnw[t + 512] * v2 * sc;
}

extern "C" void kernel_launch(void* const* d_in, const int* in_sizes, int n_in,
                              void* d_out, int out_size, void* d_ws, size_t ws_size,
                              hipStream_t stream) {
    const float* ew   = (const float*)d_in[2];
    const int*   ei   = (const int*)d_in[3];
    const float* xf   = (const float*)d_in[4];
    const float* Whid = (const float*)d_in[5];
    const float* bhid = (const float*)d_in[6];
    const float* Wout = (const float*)d_in[7];
    const float* bout = (const float*)d_in[8];
    const float* Wres = (const float*)d_in[9];
    const float* bres = (const float*)d_in[10];
    const float* lnw  = (const float*)d_in[11];

    char* ws = (char*)d_ws;
    float*  wmap = (float*)(ws);                     // 131072
    ushort* Ap   = (ushort*)(ws + 131072);           // 8192*704*2 = 11534336
    ushort* Bp   = (ushort*)(ws + 11665408);         // 1792*704*2 = 2523136
    ushort* Wb   = (ushort*)(ws + 14188544);         // 768*1024*2 = 1572864
    ushort* hidB = (ushort*)(ws + 15761408);         // 8192*1024*2 = 16777216
    ushort* resb = (ushort*)(ws + 32538624);         // 8192*768*2  = 12582912
    ushort* outb = (ushort*)(ws + 45121536);         // 8192*768*2  = 12582912
                                                     // end ~57.7 MB

    k_route<<<32, 256, 0, stream>>>(ew, ei, wmap);
    k_pack_a<<<2816, 256, 0, stream>>>(xf, wmap, Ap);
    k_pack_b<<<616, 256, 0, stream>>>(Whid, bhid, Wres, bres, Bp);
    k_pack_wout<<<384, 256, 0, stream>>>(Wout, Wb);
    k_gemm1<<<224, 512, 0, stream>>>(Ap, Bp, hidB, resb);
    k_gemm2<<<dim3(64, 6), 256, 0, stream>>>(hidB, Wb, bout, resb, outb);
    k_rms<<<8192, 256, 0, stream>>>(outb, lnw, (float*)d_out);
}

// Round 10
// 74.064 us; speedup vs baseline: 1.9870x; 1.1372x over previous
//
#include <hip/hip_runtime.h>
#include <hip/hip_bf16.h>

#define TOKENS 8192
#define D_IN   256
#define HDIM   1024
#define ODIM   768
#define KPACK  704    // 640 statically-valid cols + bias chunk + pad -> 11 x BK=64
#define NCHUNK 88     // KPACK/8

typedef short bf16x8 __attribute__((ext_vector_type(8)));
typedef float f32x4  __attribute__((ext_vector_type(4)));

static __device__ __forceinline__ ushort f2b(float f) {
    union { __hip_bfloat16 b; ushort u; } cv;
    cv.b = __float2bfloat16(f);
    return cv.u;
}
static __device__ __forceinline__ float b2f(ushort u) {
    union { ushort u; __hip_bfloat16 b; } cv;
    cv.u = u;
    return __bfloat162float(cv.b);
}

// packed chunk index (0..79) -> (expert, source col d0); static masks:
// e0: cols [0,32)u[128,160) = 8 chunks; e1: 16; e2: 24; e3: 32 chunks
static __device__ __forceinline__ void chunk_map(int c8, int& e, int& d0) {
    int cc;
    if (c8 < 8)       { e = 0; cc = c8; }
    else if (c8 < 24) { e = 1; cc = c8 - 8; }
    else if (c8 < 48) { e = 2; cc = c8 - 24; }
    else              { e = 3; cc = c8 - 48; }
    int half = 4 * (e + 1);
    d0 = (cc < half) ? cc * 8 : 128 + (cc - half) * 8;
}

// direct global->LDS DMA, 16B/lane; LDS dest = wave-uniform base + lane*16
static __device__ __forceinline__ void stage16(const ushort* g, ushort* l) {
    __builtin_amdgcn_global_load_lds(
        (const __attribute__((address_space(1))) void*)g,
        (__attribute__((address_space(3))) void*)l, 16, 0, 0);
}

// tanh-form GELU (max dev from exact erf-GELU ~3e-4)
static __device__ __forceinline__ float gelu_f(float v) {
    float y = 0.7978845608f * v * (1.f + 0.044715f * v * v);
    return v - v / (__expf(2.f * y) + 1.f);
}

// ---- K0a: pack A'' (route fused; bf16, static-compressed cols, K=704) ------
__global__ __launch_bounds__(256) void k_pack_a(
    const float* __restrict__ ew, const int* __restrict__ ei,
    const float* __restrict__ xf, ushort* __restrict__ Ap) {
    int gid = blockIdx.x * 256 + threadIdx.x;   // 8192*88 items
    int n  = gid / NCHUNK;
    int c8 = gid - n * NCHUNK;
    // inline routing (ei/ew L2-cached; 88x redundant reads are cheap)
    int   i0 = ei[2 * n], i1 = ei[2 * n + 1];
    float w0 = ew[2 * n], w1 = ew[2 * n + 1];
    bool v0 = (unsigned)i0 < 4u, v1 = (unsigned)i1 < 4u;
    float rs = (v0 ? w0 : 0.f) + (v1 ? w1 : 0.f);
    if (rs == 0.f) rs = 1.f;
    float o0 = v0 ? w0 / rs : 0.f;
    float o1 = v1 ? w1 / rs : 0.f;
    ushort o[8] __attribute__((aligned(16))) = {0, 0, 0, 0, 0, 0, 0, 0};
    if (c8 < 80) {
        int e, d0;
        chunk_map(c8, e, d0);
        float w = ((v0 && i0 == e) ? o0 : 0.f) + ((v1 && i1 == e) ? o1 : 0.f);
        if (w != 0.f) {
            const float* s = xf + ((size_t)e * TOKENS + n) * D_IN + d0;
#pragma unroll
            for (int j = 0; j < 8; ++j) {
                float v = s[j];
                if (!(v == v)) v = 0.f;   // nan_to_num
                o[j] = f2b(w * v);
            }
        }
    } else if (c8 == 80) {
#pragma unroll
        for (int j = 0; j < 4; ++j) {
            float m = ((v0 && i0 == j) ? o0 : 0.f) + ((v1 && i1 == j) ? o1 : 0.f);
            o[j] = f2b(m);
        }
    }
    *(uint4*)(Ap + (size_t)n * KPACK + c8 * 8) = *(const uint4*)o;
}

// ---- K0b: pack B'' (compressed cols, bias chunk 80) + W_out bf16, fused ----
#define BW_SPLIT (1792 * NCHUNK)   // 157696 items for B''; then 768*128 for Wout
__global__ __launch_bounds__(256) void k_pack_bw(
    const float* __restrict__ Whid, const float* __restrict__ bhid,
    const float* __restrict__ Wres, const float* __restrict__ bres,
    const float* __restrict__ Wout,
    ushort* __restrict__ Bp, ushort* __restrict__ Wb) {
    int gid = blockIdx.x * 256 + threadIdx.x;   // 256000 items total
    if (gid < BW_SPLIT) {
        int o_ = gid / NCHUNK;
        int c8 = gid - o_ * NCHUNK;
        ushort v[8] __attribute__((aligned(16))) = {0, 0, 0, 0, 0, 0, 0, 0};
        if (c8 < 80) {
            int e, d0;
            chunk_map(c8, e, d0);
            const float* s = (o_ < HDIM)
                ? Whid + ((size_t)e * HDIM + o_) * D_IN + d0
                : Wres + ((size_t)e * ODIM + (o_ - HDIM)) * D_IN + d0;
#pragma unroll
            for (int j = 0; j < 8; ++j) v[j] = f2b(s[j]);
        } else if (c8 == 80) {
#pragma unroll
            for (int j = 0; j < 4; ++j) {
                float b = (o_ < HDIM) ? bhid[j * HDIM + o_] : bres[j * ODIM + (o_ - HDIM)];
                v[j] = f2b(b);
            }
        }
        *(uint4*)(Bp + (size_t)o_ * KPACK + c8 * 8) = *(const uint4*)v;
    } else {
        int g2 = gid - BW_SPLIT;                // 768*128 items
        const float* s = Wout + (size_t)g2 * 8;
        ushort v[8] __attribute__((aligned(16)));
#pragma unroll
        for (int j = 0; j < 8; ++j) v[j] = f2b(s[j]);
        *(uint4*)(Wb + (size_t)g2 * 8) = *(const uint4*)v;
    }
}

// ---- GEMM1: 256^2, K=704 (11 tiles), 8-phase counted-vmcnt, static unroll --
__global__ __launch_bounds__(512, 2) void k_gemm1(
    const ushort* __restrict__ A, const ushort* __restrict__ B,
    ushort* __restrict__ hidB, ushort* __restrict__ resb) {
    __shared__ __align__(16) ushort As[2][256 * 64];   // 32KB each
    __shared__ __align__(16) ushort Bs[2][256 * 64];
    const int tid = threadIdx.x;
    const int lane = tid & 63, w = tid >> 6;
    const int wr = w >> 2, wc = w & 3;          // 2M x 4N wave grid
    const int r = lane & 15, g = lane >> 4;
    const int sx = r & 7;

    // XCD-bijective block swizzle: 224 blocks = 8 XCD x 28
    int bid  = blockIdx.x;
    int widx = (bid & 7) * 28 + (bid >> 3);
    int bm = widx / 7, bn = widx - bm * 7;

    const int srow = tid >> 3;                  // 0..63
    const int gc   = (tid & 7) ^ (srow & 7);
    const int wv8  = w * 8;
    const ushort* Abase = A + (size_t)(bm * 256) * KPACK;
    const ushort* Bbase = B + (size_t)(bn * 256) * KPACK;

#define STG(gsrc, grow, kc, lds, lrow)                                      \
    stage16((gsrc) + (size_t)((grow) + srow) * KPACK + ((kc) + gc) * 8,     \
            (lds) + ((lrow) + wv8) * 64)

    // prologue: tile0 -> buf0 full (8 calls); tile1 -> buf1 B + A.S0,S2 (6)
    STG(Bbase, 0, 0, &Bs[0][0], 0);     STG(Bbase, 64, 0, &Bs[0][0], 64);
    STG(Bbase, 128, 0, &Bs[0][0], 128); STG(Bbase, 192, 0, &Bs[0][0], 192);
    STG(Abase, 0, 0, &As[0][0], 0);     STG(Abase, 64, 0, &As[0][0], 64);
    STG(Abase, 128, 0, &As[0][0], 128); STG(Abase, 192, 0, &As[0][0], 192);
    STG(Bbase, 0, 8, &Bs[1][0], 0);     STG(Bbase, 64, 8, &Bs[1][0], 64);
    STG(Bbase, 128, 8, &Bs[1][0], 128); STG(Bbase, 192, 8, &Bs[1][0], 192);
    STG(Abase, 0, 8, &As[1][0], 0);     STG(Abase, 128, 8, &As[1][0], 128);
    asm volatile("s_waitcnt vmcnt(6)" ::: "memory");
    __builtin_amdgcn_s_barrier();

    f32x4 acc[8][4] = {};
    bf16x8 af[2][2], bfr[4][2];

#define LD_A(buf, mi, ks) (*(const bf16x8*)&As[buf][(wr * 128 + (mi) * 16 + r) * 64 + ((((ks) * 4 + g) ^ sx) * 8)])
#define LD_B(buf, j, ks)  (*(const bf16x8*)&Bs[buf][(wc * 64  + (j) * 16 + r) * 64 + ((((ks) * 4 + g) ^ sx) * 8)])
#define READ_A(buf, qq) do {                                                  \
    af[0][0] = LD_A(buf, 2 * (qq), 0);     af[0][1] = LD_A(buf, 2 * (qq), 1); \
    af[1][0] = LD_A(buf, 2 * (qq) + 1, 0); af[1][1] = LD_A(buf, 2 * (qq) + 1, 1); } while (0)
#define READ_B(buf) do { _Pragma("unroll")                                   \
    for (int j_ = 0; j_ < 4; ++j_) { bfr[j_][0] = LD_B(buf, j_, 0); bfr[j_][1] = LD_B(buf, j_, 1); } } while (0)
#define MFMA_Q(qq) do {                                                      \
    __builtin_amdgcn_s_setprio(1);                                           \
    _Pragma("unroll") for (int i_ = 0; i_ < 2; ++i_)                         \
    _Pragma("unroll") for (int k_ = 0; k_ < 2; ++k_)                         \
    _Pragma("unroll") for (int j_ = 0; j_ < 4; ++j_)                         \
        acc[2 * (qq) + i_][j_] = __builtin_amdgcn_mfma_f32_16x16x32_bf16(    \
            af[i_][k_], bfr[j_][k_], acc[2 * (qq) + i_][j_], 0, 0, 0);       \
    __builtin_amdgcn_s_setprio(0); } while (0)
#define OPEN_BAR() do { __builtin_amdgcn_sched_barrier(0);                   \
    __builtin_amdgcn_s_barrier(); } while (0)

#pragma unroll
    for (int i = 0; i < 5; ++i) {               // 2 tiles/iter; tiles 0..9
        const int kcp = (2 * i + 1) * 8;        // tile 2i+1 -> buf1 A S1,S3
        const int kc0 = (2 * i + 2) * 8;        // tile 2i+2 -> buf0 (always <11)
        const int kc1 = (2 * i + 3) * 8;        // tile 2i+3 -> buf1 (if st1)
        const bool st1 = (i < 4);
        // p1: read buf0 {B, Aq0}; stage buf1.A S1,S3
        READ_B(0); READ_A(0, 0);
        STG(Abase, 64, kcp, &As[1][0], 64);
        STG(Abase, 192, kcp, &As[1][0], 192);
        OPEN_BAR(); MFMA_Q(0); __builtin_amdgcn_s_barrier();
        // p2
        READ_A(0, 1);
        STG(Bbase, 0, kc0, &Bs[0][0], 0);
        STG(Bbase, 64, kc0, &Bs[0][0], 64);
        OPEN_BAR(); MFMA_Q(1);
        // p3
        READ_A(0, 2);
        STG(Bbase, 128, kc0, &Bs[0][0], 128);
        STG(Bbase, 192, kc0, &Bs[0][0], 192);
        OPEN_BAR(); MFMA_Q(2);
        // p4 + publish buf1 (vmcnt(6) = p2..p4's 6 stages may fly)
        READ_A(0, 3);
        STG(Abase, 0, kc0, &As[0][0], 0);
        STG(Abase, 128, kc0, &As[0][0], 128);
        OPEN_BAR(); MFMA_Q(3);
        asm volatile("s_waitcnt vmcnt(6)" ::: "memory");
        __builtin_amdgcn_s_barrier();
        // p5: read buf1 {B, Aq0}; stage buf0.A S1,S3
        READ_B(1); READ_A(1, 0);
        STG(Abase, 64, kc0, &As[0][0], 64);
        STG(Abase, 192, kc0, &As[0][0], 192);
        OPEN_BAR(); MFMA_Q(0); __builtin_amdgcn_s_barrier();
        // p6
        READ_A(1, 1);
        if (st1) { STG(Bbase, 0, kc1, &Bs[1][0], 0);
                   STG(Bbase, 64, kc1, &Bs[1][0], 64); }
        OPEN_BAR(); MFMA_Q(1);
        // p7
        READ_A(1, 2);
        if (st1) { STG(Bbase, 128, kc1, &Bs[1][0], 128);
                   STG(Bbase, 192, kc1, &Bs[1][0], 192); }
        OPEN_BAR(); MFMA_Q(2);
        // p8 + publish buf0 (drain fully before tail on last iter)
        READ_A(1, 3);
        if (st1) { STG(Abase, 0, kc1, &As[1][0], 0);
                   STG(Abase, 128, kc1, &As[1][0], 128); }
        OPEN_BAR(); MFMA_Q(3);
        if (st1) asm volatile("s_waitcnt vmcnt(6)" ::: "memory");
        else     asm volatile("s_waitcnt vmcnt(0)" ::: "memory");
        __builtin_amdgcn_s_barrier();
    }
    // tail: tile 10 from buf0 (fully drained); no concurrent writers
    READ_B(0); READ_A(0, 0); MFMA_Q(0);
    READ_A(0, 1); MFMA_Q(1);
    READ_A(0, 2); MFMA_Q(2);
    READ_A(0, 3); MFMA_Q(3);
#undef STG
#undef LD_A
#undef LD_B
#undef READ_A
#undef READ_B
#undef MFMA_Q
#undef OPEN_BAR

#pragma unroll
    for (int fi = 0; fi < 8; ++fi) {
#pragma unroll
        for (int j = 0; j < 4; ++j) {
            int col = bn * 256 + wc * 64 + j * 16 + r;
#pragma unroll
            for (int qq = 0; qq < 4; ++qq) {
                int row = bm * 256 + wr * 128 + fi * 16 + g * 4 + qq;
                float v = acc[fi][j][qq];
                if (col < HDIM) {
                    hidB[(size_t)row * HDIM + col] = f2b(gelu_f(v));
                } else {
                    resb[(size_t)row * ODIM + (col - HDIM)] = f2b(v);
                }
            }
        }
    }
}

// ---- GEMM2: 128^2 tile, BK=64, depth-2 pipeline with EARLY staging ---------
// Iter: vmcnt(8)+bar (publish cur) -> 16 ds_reads -> lgkmcnt(0)+bar (all
// waves' reads done) -> STG(t+2 -> cur) issued BEFORE MFMA (overlaps the
// 32-MFMA cluster + next read window) -> MFMA. 2 blocks/CU cross-overlap.
__global__ __launch_bounds__(256, 2) void k_gemm2(
    const ushort* __restrict__ A, const ushort* __restrict__ B,
    const float* __restrict__ bout, const ushort* __restrict__ resb,
    ushort* __restrict__ outb) {
    __shared__ __align__(16) ushort As[2][128 * 64];
    __shared__ __align__(16) ushort Bs[2][128 * 64];
    const int tid = threadIdx.x;
    const int lane = tid & 63, w = tid >> 6;
    const int wr = w >> 1, wc = w & 1;
    const int r = lane & 15, g = lane >> 4;
    const int bm = blockIdx.x, bn = blockIdx.y;

    const int srow = tid >> 3;
    const int gc   = (tid & 7) ^ (srow & 7);
    const ushort* Ag = A + (size_t)(bm * 128 + srow) * HDIM + gc * 8;
    const ushort* Bg = B + (size_t)(bn * 128 + srow) * HDIM + gc * 8;
    const int ldst = (w * 8) * 64;

#define G2_STAGE(p, kt) do {                                            \
    _Pragma("unroll")                                                   \
    for (int i_ = 0; i_ < 4; ++i_) {                                    \
        stage16(Ag + (size_t)(i_ * 32) * HDIM + (kt), &As[p][ldst + i_ * 32 * 64]); \
        stage16(Bg + (size_t)(i_ * 32) * HDIM + (kt), &Bs[p][ldst + i_ * 32 * 64]); \
    } } while (0)

    G2_STAGE(0, 0);
    G2_STAGE(1, 64);

    f32x4 acc[4][4] = {};
    const int cA = (wr * 64 + r) * 64;
    const int cB = (wc * 64 + r) * 64;
    const int sx = r & 7;
    const int cs0 = ((0 * 4 + g) ^ sx) * 8;
    const int cs1 = ((1 * 4 + g) ^ sx) * 8;

    int cur = 0;
#pragma unroll
    for (int t = 0; t < 16; ++t) {
        if (t < 15) asm volatile("s_waitcnt vmcnt(8)" ::: "memory");
        else        asm volatile("s_waitcnt vmcnt(0)" ::: "memory");
        __builtin_amdgcn_s_barrier();
        const ushort* Ab = As[cur];
        const ushort* Bb = Bs[cur];
        bf16x8 a0[4], b0[4], a1[4], b1[4];
#pragma unroll
        for (int j = 0; j < 4; ++j) {
            b0[j] = *(const bf16x8*)&Bb[cB + j * 16 * 64 + cs0];
            b1[j] = *(const bf16x8*)&Bb[cB + j * 16 * 64 + cs1];
        }
#pragma unroll
        for (int i = 0; i < 4; ++i) {
            a0[i] = *(const bf16x8*)&Ab[cA + i * 16 * 64 + cs0];
            a1[i] = *(const bf16x8*)&Ab[cA + i * 16 * 64 + cs1];
        }
        asm volatile("s_waitcnt lgkmcnt(0)" ::: "memory");
        __builtin_amdgcn_sched_barrier(0);
        __builtin_amdgcn_s_barrier();
        if (t + 2 < 16) G2_STAGE(cur, (t + 2) * 64);   // early issue, overlaps MFMA
        __builtin_amdgcn_s_setprio(1);
#pragma unroll
        for (int i = 0; i < 4; ++i)
#pragma unroll
            for (int j = 0; j < 4; ++j)
                acc[i][j] = __builtin_amdgcn_mfma_f32_16x16x32_bf16(
                    a0[i], b0[j], acc[i][j], 0, 0, 0);
#pragma unroll
        for (int i = 0; i < 4; ++i)
#pragma unroll
            for (int j = 0; j < 4; ++j)
                acc[i][j] = __builtin_amdgcn_mfma_f32_16x16x32_bf16(
                    a1[i], b1[j], acc[i][j], 0, 0, 0);
        __builtin_amdgcn_s_setprio(0);
        cur ^= 1;
    }
#undef G2_STAGE

#pragma unroll
    for (int fi = 0; fi < 4; ++fi) {
#pragma unroll
        for (int j = 0; j < 4; ++j) {
            int col = bn * 128 + wc * 64 + j * 16 + r;
#pragma unroll
            for (int qq = 0; qq < 4; ++qq) {
                int row = bm * 128 + wr * 64 + fi * 16 + g * 4 + qq;
                size_t idx = (size_t)row * ODIM + col;
                float v = acc[fi][j][qq] + bout[col] + b2f(resb[idx]);
                outb[idx] = f2b(v);
            }
        }
    }
}

// ---- RMS norm row-wise (bf16 in, f32 out) ----------------------------------
__global__ __launch_bounds__(256) void k_rms(
    const ushort* __restrict__ outb, const float* __restrict__ lnw,
    float* __restrict__ out) {
    int row = blockIdx.x, t = threadIdx.x;
    const ushort* p = outb + (size_t)row * ODIM;
    float v0 = b2f(p[t]), v1 = b2f(p[t + 256]), v2 = b2f(p[t + 512]);
    float s = v0 * v0 + v1 * v1 + v2 * v2;
#pragma unroll
    for (int off = 32; off > 0; off >>= 1) s += __shfl_down(s, off, 64);
    __shared__ float ws4[4];
    if ((t & 63) == 0) ws4[t >> 6] = s;
    __syncthreads();
    float tot = ws4[0] + ws4[1] + ws4[2] + ws4[3];
    float sc = rsqrtf(tot * (1.f / 768.f) + 1e-6f);
    out[(size_t)row * ODIM + t]       = lnw[t]       * v0 * sc;
    out[(size_t)row * ODIM + t + 256] = lnw[t + 256] * v1 * sc;
    out[(size_t)row * ODIM + t + 512] = lnw[t + 512] * v2 * sc;
}

extern "C" void kernel_launch(void* const* d_in, const int* in_sizes, int n_in,
                              void* d_out, int out_size, void* d_ws, size_t ws_size,
                              hipStream_t stream) {
    const float* ew   = (const float*)d_in[2];
    const int*   ei   = (const int*)d_in[3];
    const float* xf   = (const float*)d_in[4];
    const float* Whid = (const float*)d_in[5];
    const float* bhid = (const float*)d_in[6];
    const float* Wout = (const float*)d_in[7];
    const float* bout = (const float*)d_in[8];
    const float* Wres = (const float*)d_in[9];
    const float* bres = (const float*)d_in[10];
    const float* lnw  = (const float*)d_in[11];

    char* ws = (char*)d_ws;
    ushort* Ap   = (ushort*)(ws);                    // 8192*704*2 = 11534336
    ushort* Bp   = (ushort*)(ws + 11534336);         // 1792*704*2 = 2523136
    ushort* Wb   = (ushort*)(ws + 14057472);         // 768*1024*2 = 1572864
    ushort* hidB = (ushort*)(ws + 15630336);         // 8192*1024*2 = 16777216
    ushort* resb = (ushort*)(ws + 32407552);         // 8192*768*2  = 12582912
    ushort* outb = (ushort*)(ws + 44990464);         // 8192*768*2  = 12582912
                                                     // end ~57.6 MB

    k_pack_a<<<2816, 256, 0, stream>>>(ew, ei, xf, Ap);
    k_pack_bw<<<1000, 256, 0, stream>>>(Whid, bhid, Wres, bres, Wout, Bp, Wb);
    k_gemm1<<<224, 512, 0, stream>>>(Ap, Bp, hidB, resb);
    k_gemm2<<<dim3(64, 6), 256, 0, stream>>>(hidB, Wb, bout, resb, outb);
    k_rms<<<8192, 256, 0, stream>>>(outb, lnw, (float*)d_out);
}